// Round 1
// baseline (457.952 us; speedup 1.0000x reference)
//
#include <hip/hip_runtime.h>

// DynamicRouting: votes [B=32, NIN=2048, NOUT=64, ATOMS=16] fp32, 3 routing iters.
// Strategy: 3 streaming passes over votes. Pass k computes
//   logits = <votes, pose_accum>  (pose_accum = sum of previous poses; 0-th pass c=1/64)
//   c = softmax over out axis (64 lanes = 64 out caps, shuffle softmax)
//   preact[b,out,:] += c * votes[b,in,out,:]   (block LDS reduce + atomicAdd)
// then a tiny squash kernel produces pose (and accumulates pose_accum / writes output).

#define NB 32
#define NIN 2048
#define NOUT 64
#define ATOMS 16
#define EPSF 1e-9f

#define ROWS_PER_WAVE 32
#define WAVES_PER_BLOCK 4
#define ROWS_PER_BLOCK (ROWS_PER_WAVE * WAVES_PER_BLOCK) // 128
#define CHUNKS (NIN / ROWS_PER_BLOCK)                    // 16

template <int USE_POSE>
__global__ __launch_bounds__(256) void route_pass(
    const float* __restrict__ votes,
    const float* __restrict__ pose_accum,
    float* __restrict__ preact)
{
    const int b    = blockIdx.x / CHUNKS;
    const int chunk = blockIdx.x % CHUNKS;
    const int wave = threadIdx.x >> 6;
    const int lane = threadIdx.x & 63; // = out-capsule index

    // pose fragment for this lane's out-capsule, in registers
    float pose[ATOMS];
    if (USE_POSE) {
        const float4* p4 = reinterpret_cast<const float4*>(pose_accum) + (b * NOUT + lane) * 4;
        float4 q0 = p4[0], q1 = p4[1], q2 = p4[2], q3 = p4[3];
        pose[0]=q0.x; pose[1]=q0.y; pose[2]=q0.z; pose[3]=q0.w;
        pose[4]=q1.x; pose[5]=q1.y; pose[6]=q1.z; pose[7]=q1.w;
        pose[8]=q2.x; pose[9]=q2.y; pose[10]=q2.z; pose[11]=q2.w;
        pose[12]=q3.x; pose[13]=q3.y; pose[14]=q3.z; pose[15]=q3.w;
    }

    float acc[ATOMS];
#pragma unroll
    for (int a = 0; a < ATOMS; ++a) acc[a] = 0.0f;

    const int in0 = chunk * ROWS_PER_BLOCK + wave * ROWS_PER_WAVE;
    const float4* vrow = reinterpret_cast<const float4*>(votes)
                       + ((size_t)(b * NIN + in0) * NOUT + lane) * (ATOMS / 4);

#pragma unroll 2
    for (int r = 0; r < ROWS_PER_WAVE; ++r) {
        const float4* vp = vrow + (size_t)r * (NOUT * (ATOMS / 4));
        float4 c0 = vp[0], c1 = vp[1], c2 = vp[2], c3 = vp[3];
        float v[ATOMS];
        v[0]=c0.x; v[1]=c0.y; v[2]=c0.z; v[3]=c0.w;
        v[4]=c1.x; v[5]=c1.y; v[6]=c1.z; v[7]=c1.w;
        v[8]=c2.x; v[9]=c2.y; v[10]=c2.z; v[11]=c2.w;
        v[12]=c3.x; v[13]=c3.y; v[14]=c3.z; v[15]=c3.w;

        float cc;
        if (USE_POSE) {
            float logit = 0.0f;
#pragma unroll
            for (int a = 0; a < ATOMS; ++a) logit = fmaf(v[a], pose[a], logit);
            // softmax across the 64 out-caps (the full wave)
            float m = logit;
#pragma unroll
            for (int mask = 32; mask >= 1; mask >>= 1)
                m = fmaxf(m, __shfl_xor(m, mask, 64));
            float e = __expf(logit - m);
            float s = e;
#pragma unroll
            for (int mask = 32; mask >= 1; mask >>= 1)
                s += __shfl_xor(s, mask, 64);
            cc = e / s;
        } else {
            cc = 1.0f / 64.0f; // softmax of all-zero logits
        }
#pragma unroll
        for (int a = 0; a < ATOMS; ++a) acc[a] = fmaf(cc, v[a], acc[a]);
    }

    // block-level reduction across the 4 waves, then one atomicAdd set per block
    __shared__ float red[WAVES_PER_BLOCK * NOUT * ATOMS]; // 16 KiB
#pragma unroll
    for (int a = 0; a < ATOMS; ++a)
        red[(wave * NOUT + lane) * ATOMS + a] = acc[a];
    __syncthreads();

    for (int idx = threadIdx.x; idx < NOUT * ATOMS; idx += 256) {
        float t = red[idx] + red[NOUT * ATOMS + idx]
                + red[2 * NOUT * ATOMS + idx] + red[3 * NOUT * ATOMS + idx];
        atomicAdd(&preact[b * NOUT * ATOMS + idx], t);
    }
}

// mode 0: pose_accum = pose ; mode 1: pose_accum += pose ; mode 2: write d_out (pose + prob)
__global__ __launch_bounds__(256) void squash_k(
    const float* __restrict__ preact,
    float* __restrict__ pose_accum,
    float* __restrict__ d_out,
    int mode)
{
    int idx = blockIdx.x * 256 + threadIdx.x; // < NB*NOUT*ATOMS, 16 lanes per (b,out)
    float s = preact[idx];
    float sq = s * s;
#pragma unroll
    for (int mask = 1; mask < ATOMS; mask <<= 1)
        sq += __shfl_xor(sq, mask, 64);
    float norm = sqrtf(sq + EPSF);
    float f = (sq / (1.0f + sq)) / norm;
    float p = f * s;
    if (mode == 0) {
        pose_accum[idx] = p;
    } else if (mode == 1) {
        pose_accum[idx] += p;
    } else {
        d_out[idx] = p;
        if ((idx & (ATOMS - 1)) == 0) {
            float psq = f * f * sq; // sum over atoms of pose^2
            d_out[NB * NOUT * ATOMS + (idx >> 4)] = sqrtf(psq + EPSF);
        }
    }
}

extern "C" void kernel_launch(void* const* d_in, const int* in_sizes, int n_in,
                              void* d_out, int out_size, void* d_ws, size_t ws_size,
                              hipStream_t stream) {
    const float* votes = (const float*)d_in[0];
    float* out = (float*)d_out;

    float* preact     = (float*)d_ws;                 // 32768 floats
    float* pose_accum = preact + NB * NOUT * ATOMS;   // 32768 floats
    const size_t pre_bytes = (size_t)NB * NOUT * ATOMS * sizeof(float);

    dim3 blk(256);
    dim3 grid_route(NB * CHUNKS);                 // 512 blocks
    dim3 grid_sq(NB * NOUT * ATOMS / 256);        // 128 blocks

    // ---- iteration 0: c = 1/64 uniform ----
    hipMemsetAsync(preact, 0, pre_bytes, stream);
    route_pass<0><<<grid_route, blk, 0, stream>>>(votes, nullptr, preact);
    squash_k<<<grid_sq, blk, 0, stream>>>(preact, pose_accum, nullptr, 0);

    // ---- iteration 1: logits = <votes, pose0> ----
    hipMemsetAsync(preact, 0, pre_bytes, stream);
    route_pass<1><<<grid_route, blk, 0, stream>>>(votes, pose_accum, preact);
    squash_k<<<grid_sq, blk, 0, stream>>>(preact, pose_accum, nullptr, 1);

    // ---- iteration 2: logits = <votes, pose0+pose1> ----
    hipMemsetAsync(preact, 0, pre_bytes, stream);
    route_pass<1><<<grid_route, blk, 0, stream>>>(votes, pose_accum, preact);
    squash_k<<<grid_sq, blk, 0, stream>>>(preact, nullptr, out, 2);
}